// Round 8
// baseline (301.661 us; speedup 1.0000x reference)
//
#include <hip/hip_runtime.h>
#include <hip/hip_bf16.h>
#include <stdint.h>

#define T_SEQ 4096
#define KVB 64
#define BM 128
#define BN 128
#define BK 64
#define SCL2 (0.08838834764831845f * 1.44269504088896340f)

typedef unsigned short u16;
typedef __attribute__((ext_vector_type(8))) short s16x8;
typedef __attribute__((ext_vector_type(4))) short s16x4;
typedef __attribute__((ext_vector_type(4))) float f32x4;

__device__ __forceinline__ u16 f2bf(float f) {
  union { float f; unsigned u; } a; a.f = f;
  unsigned r = a.u + 0x7fffu + ((a.u >> 16) & 1u);
  return (u16)(r >> 16);
}
__device__ __forceinline__ float bf2f(u16 b) {
  union { unsigned u; float f; } a; a.u = ((unsigned)b) << 16;
  return a.f;
}
__device__ __forceinline__ unsigned cvtpk(float lo, float hi) {
  unsigned r;
  asm volatile("v_cvt_pk_bf16_f32 %0, %1, %2" : "=v"(r) : "v"(lo), "v"(hi));
  return r;
}

__device__ __forceinline__ void gl_lds16(const void* g, void* l) {
  __builtin_amdgcn_global_load_lds((const __attribute__((address_space(1))) void*)g,
                                   (__attribute__((address_space(3))) void*)l, 16, 0, 0);
}

// ---------------- fp32 -> bf16 convert (hidden) ----------------
__global__ __launch_bounds__(256) void k_cvt(const float* __restrict__ in, u16* __restrict__ out) {
  int i = (blockIdx.x * 256 + threadIdx.x) * 8;
  const float4* p = (const float4*)(in + i);
  float4 a = p[0], b = p[1];
  s16x8 o;
  o[0] = (short)f2bf(a.x); o[1] = (short)f2bf(a.y); o[2] = (short)f2bf(a.z); o[3] = (short)f2bf(a.w);
  o[4] = (short)f2bf(b.x); o[5] = (short)f2bf(b.y); o[6] = (short)f2bf(b.z); o[7] = (short)f2bf(b.w);
  *(s16x8*)(out + i) = o;
}

// ---------------- transpose + convert weights: out[c][r] = bf16(in[r][c]) ----------------
__global__ __launch_bounds__(256) void k_transpose_cvt(const float* __restrict__ in, u16* __restrict__ out,
                                                       int R, int C) {
  __shared__ float tile[32][33];
  int c0 = blockIdx.x * 32, r0 = blockIdx.y * 32;
  int tx = threadIdx.x & 31, ty = threadIdx.x >> 5;
#pragma unroll
  for (int k = 0; k < 4; k++) tile[ty + 8 * k][tx] = in[(size_t)(r0 + ty + 8 * k) * C + c0 + tx];
  __syncthreads();
#pragma unroll
  for (int k = 0; k < 4; k++) out[(size_t)(c0 + ty + 8 * k) * R + r0 + tx] = f2bf(tile[tx][ty + 8 * k]);
}

// ---------------- GEMM: C[m][n] = sum_k A[m][k]*Bt[n][k]  (A,Bt bf16) ----------------
__global__ __launch_bounds__(256, 2) void k_gemm(const u16* __restrict__ A, const u16* __restrict__ Bt,
                                                 u16* __restrict__ Cq, u16* __restrict__ Ck, u16* __restrict__ Cvt,
                                                 float* __restrict__ Cf, int M, int N, int Kd, int mode) {
  __shared__ u16 SM[BM * BK + BN * BK];
  u16* As = SM;
  u16* Bs = SM + BM * BK;
  int tid = threadIdx.x, lane = tid & 63, w = tid >> 6;
  int g = lane >> 4, r16 = lane & 15;
  int m0 = blockIdx.y * BM, n0 = blockIdx.x * BN;
  int wr = w >> 1, wc = w & 1;
  f32x4 acc[4][4] = {};

  for (int kt = 0; kt < Kd; kt += BK) {
#pragma unroll
    for (int i = 0; i < 4; i++) {
      int idx = i * 256 + tid;
      int row = idx >> 3, c = idx & 7;
      int cs = c ^ (row & 7);
      gl_lds16(A + (size_t)(m0 + row) * Kd + kt + cs * 8, As + (i * 256 + w * 64) * 8);
    }
#pragma unroll
    for (int i = 0; i < 4; i++) {
      int idx = i * 256 + tid;
      int row = idx >> 3, c = idx & 7;
      int cs = c ^ (row & 7);
      gl_lds16(Bt + (size_t)(n0 + row) * Kd + kt + cs * 8, Bs + (i * 256 + w * 64) * 8);
    }
    __syncthreads();
#pragma unroll
    for (int kk = 0; kk < 2; kk++) {
      s16x8 af[4], bfr[4];
#pragma unroll
      for (int mi = 0; mi < 4; mi++) {
        int row = wr * 64 + mi * 16 + r16;
        af[mi] = *(const s16x8*)(As + row * 64 + (((kk * 4 + g) ^ (row & 7)) * 8));
      }
#pragma unroll
      for (int ni = 0; ni < 4; ni++) {
        int row = wc * 64 + ni * 16 + r16;
        bfr[ni] = *(const s16x8*)(Bs + row * 64 + (((kk * 4 + g) ^ (row & 7)) * 8));
      }
#pragma unroll
      for (int mi = 0; mi < 4; mi++)
#pragma unroll
        for (int ni = 0; ni < 4; ni++)
          acc[mi][ni] = __builtin_amdgcn_mfma_f32_16x16x32_bf16(af[mi], bfr[ni], acc[mi][ni], 0, 0, 0);
    }
    __syncthreads();
  }

#pragma unroll
  for (int mi = 0; mi < 4; mi++) {
    int rowb = m0 + wr * 64 + mi * 16 + g * 4;
#pragma unroll
    for (int ni = 0; ni < 4; ni++) {
      int ncol0 = n0 + wc * 64 + ni * 16;
      int col = ncol0 + r16;
      if (mode == 0) {
        if (ncol0 < 2048) {
#pragma unroll
          for (int j = 0; j < 4; j++) Cq[(size_t)(rowb + j) * 2048 + col] = f2bf(acc[mi][ni][j]);
        } else if (ncol0 < 2560) {
#pragma unroll
          for (int j = 0; j < 4; j++) Ck[(size_t)(rowb + j) * 512 + (col - 2048)] = f2bf(acc[mi][ni][j]);
        } else {
          s16x4 pk;
#pragma unroll
          for (int j = 0; j < 4; j++) pk[j] = (short)f2bf(acc[mi][ni][j]);
          *(s16x4*)(Cvt + (size_t)(col - 2560) * T_SEQ + rowb) = pk;
        }
      } else {
#pragma unroll
        for (int j = 0; j < 4; j++) Cf[(size_t)(rowb + j) * N + col] = acc[mi][ni][j];
      }
    }
  }
}

// ---------------- RMSNorm + RoPE (+ fold attention scale into Q) ----------------
__global__ __launch_bounds__(256) void k_normrope(u16* __restrict__ Q, u16* __restrict__ Kc,
                                                  const float* __restrict__ sinT, const float* __restrict__ cosT,
                                                  const float* __restrict__ qsc, const float* __restrict__ ksc) {
  int t = blockIdx.x;
  int w = threadIdx.x >> 6, lane = threadIdx.x & 63;
  int unit = blockIdx.y * 4 + w;  // 0..15 Q heads, 16..19 K heads
  u16* base;
  const float* sc;
  float fold;
  if (unit < 16) { base = Q + (size_t)t * 2048 + unit * 128; sc = qsc; fold = SCL2; }
  else { base = Kc + (size_t)t * 512 + (unit - 16) * 128; sc = ksc; fold = 1.0f; }
  float x1 = bf2f(base[lane]), x2 = bf2f(base[lane + 64]);
  float ss = x1 * x1 + x2 * x2;
#pragma unroll
  for (int off = 32; off >= 1; off >>= 1) ss += __shfl_xor(ss, off);
  float rinv = rsqrtf(ss * (1.0f / 128.0f) + 1e-6f);
  float n1 = x1 * rinv * sc[lane], n2 = x2 * rinv * sc[lane + 64];
  float s = sinT[t * 64 + lane], c = cosT[t * 64 + lane];
  base[lane] = f2bf((n1 * c - n2 * s) * fold);
  base[lane + 64] = f2bf((n2 * c + n1 * s) * fold);
}

// ---------------- Flash attention (causal GQA) — 3 blocks/CU, in-register P ----------------
// Q [T][2048] bf16 (pre-scaled by SCALE*log2e), Kc [T][512], Vt [512][T], O [T][2048]
// 1024 blocks x 256 thr. Wave (qs,ks): 32 q-rows x 32-key slice. LDS 48KB: K dbuf 2x16K | V 16K.
// P never touches LDS: cvt_pk + 8 __shfl + 4 select redistribute to the PV B-fragment layout.
// (select must use the DEST lane's g AFTER the shuffle — R7's pre-shuffle select was the bug.)
// Two barriers/tile: [issue K(t+1); QK; softmax] A [PV] B [issue V(t+1)].
__global__ __launch_bounds__(256, 3) void k_attn(const u16* __restrict__ Q, const u16* __restrict__ Kc,
                                                 const u16* __restrict__ Vt, u16* __restrict__ O) {
  __shared__ __align__(16) char SMc[49152];
  int tid = threadIdx.x, lane = tid & 63, w = tid >> 6;
  int g = lane >> 4, r16 = lane & 15;
  int qs = w >> 1, ks = w & 1;

  // XCD chunking (2 heads/XCD -> K/V L2-resident) + LPT (long qb first, backfill via 1024 > resident)
  int bid = blockIdx.x;
  int xcd = bid & 7;
  int lid = bid >> 3;            // 0..127 within XCD
  int h = xcd * 2 + (lid & 1);
  int qb = 63 - (lid >> 1);      // descending work
  int gh = h >> 2;
  int q0 = qb * 64;
  int qwv = q0 + qs * 32;
  int nt = qb + 1;

  s16x8 qf[2][4];
#pragma unroll
  for (int qc = 0; qc < 2; qc++)
#pragma unroll
    for (int dc = 0; dc < 4; dc++)
      qf[qc][dc] = *(const s16x8*)(Q + (size_t)(qwv + qc * 16 + r16) * 2048 + h * 128 + dc * 32 + g * 8);

  auto STAGE_K = [&](int bb, int tt) {
    int kv0 = tt * KVB;
    u16* Kb = (u16*)(SMc + bb * 16384);
#pragma unroll
    for (int i = 0; i < 4; i++) {
      int idx = i * 256 + tid;
      int row = idx >> 4, cc = idx & 15;
      int cs = cc ^ (row & 7);
      gl_lds16(Kc + (size_t)(kv0 + row) * 512 + gh * 128 + cs * 8, Kb + (i * 256 + w * 64) * 8);
    }
  };
  auto STAGE_V = [&](int tt) {
    int kv0 = tt * KVB;
    u16* Vb = (u16*)(SMc + 32768);
#pragma unroll
    for (int i = 0; i < 4; i++) {
      int idx = i * 256 + tid;
      int row = idx >> 3, cc = idx & 7;
      int cs = cc ^ (row & 7);
      gl_lds16(Vt + (size_t)(gh * 128 + row) * T_SEQ + kv0 + cs * 8, Vb + (i * 256 + w * 64) * 8);
    }
  };

  f32x4 acc[2][8] = {};
  float mrun[2] = {-3.0e38f, -3.0e38f};
  float lrun[2] = {0.0f, 0.0f};

  STAGE_K(0, 0);
  STAGE_V(0);
  __syncthreads();

  for (int t = 0; t < nt; ++t) {
    int kv0 = t * KVB;
    int bb = t & 1;
    if (t + 1 < nt) STAGE_K(bb ^ 1, t + 1);  // prefetch next K (dbuf)

    int kvw = kv0 + ks * 32;  // this wave's 32-key slice
    bool live = (kvw <= qwv + 31);
    s16x8 pfr[2];
    if (live) {
      u16* Kb = (u16*)(SMc + bb * 16384);
      // S = K @ Q^T : sv[qc][kc] lane holds key = kvw+kc*16+g*4+reg, q = qwv+qc*16+r16
      f32x4 sv[2][2] = {};
      __builtin_amdgcn_s_setprio(1);
#pragma unroll
      for (int kc = 0; kc < 2; kc++) {
        int krow = ks * 32 + kc * 16 + r16;
#pragma unroll
        for (int dc = 0; dc < 4; dc++) {
          s16x8 kf = *(const s16x8*)(Kb + krow * 128 + (((dc * 4 + g) ^ (krow & 7)) * 8));
          sv[0][kc] = __builtin_amdgcn_mfma_f32_16x16x32_bf16(kf, qf[0][dc], sv[0][kc], 0, 0, 0);
          sv[1][kc] = __builtin_amdgcn_mfma_f32_16x16x32_bf16(kf, qf[1][dc], sv[1][kc], 0, 0, 0);
        }
      }
      __builtin_amdgcn_s_setprio(0);

#pragma unroll
      for (int qc = 0; qc < 2; qc++) {
        int qg = qwv + qc * 16 + r16;
        bool needmask = (kvw + 31) > (qwv + qc * 16);
        if (needmask) {
#pragma unroll
          for (int kc = 0; kc < 2; kc++)
#pragma unroll
            for (int j2 = 0; j2 < 4; j2++)
              if (kvw + kc * 16 + g * 4 + j2 > qg) sv[qc][kc][j2] = -3.0e38f;
        }
        float mt = sv[qc][0][0];
#pragma unroll
        for (int kc = 0; kc < 2; kc++)
#pragma unroll
          for (int j2 = 0; j2 < 4; j2++) mt = fmaxf(mt, sv[qc][kc][j2]);
        mt = fmaxf(mt, __shfl_xor(mt, 16));
        mt = fmaxf(mt, __shfl_xor(mt, 32));
        // defer-max (T13)
        if (__any(mt > mrun[qc] + 8.0f)) {
          float mnew = fmaxf(mrun[qc], mt);
          float al = exp2f(mrun[qc] - mnew);
          mrun[qc] = mnew;
          lrun[qc] *= al;
#pragma unroll
          for (int df = 0; df < 8; df++) acc[qc][df] = acc[qc][df] * al;
        }
        float p00 = exp2f(sv[qc][0][0] - mrun[qc]);
        float p01 = exp2f(sv[qc][0][1] - mrun[qc]);
        float p02 = exp2f(sv[qc][0][2] - mrun[qc]);
        float p03 = exp2f(sv[qc][0][3] - mrun[qc]);
        float p10 = exp2f(sv[qc][1][0] - mrun[qc]);
        float p11 = exp2f(sv[qc][1][1] - mrun[qc]);
        float p12 = exp2f(sv[qc][1][2] - mrun[qc]);
        float p13 = exp2f(sv[qc][1][3] - mrun[qc]);
        float rs = ((p00 + p01) + (p02 + p03)) + ((p10 + p11) + (p12 + p13));
        rs += __shfl_xor(rs, 16);
        rs += __shfl_xor(rs, 32);
        lrun[qc] += rs;
        // in-register P -> PV B-fragment: lane (g,r16) needs keys g*8..g*8+7, q=r16.
        // Source lane (g',r16) holds w0=keys g'*4+{0,1}, w1=g'*4+{2,3} (kc=0),
        // w2=16+g'*4+{0,1}, w3=16+g'*4+{2,3} (kc=1). Dest pulls from g'=2(g&1),2(g&1)+1;
        // word pair (w0,w1) if g<2 else (w2,w3) — selected AFTER the shuffle with dest's g.
        unsigned w0 = cvtpk(p00, p01);
        unsigned w1 = cvtpk(p02, p03);
        unsigned w2 = cvtpk(p10, p11);
        unsigned w3 = cvtpk(p12, p13);
        int sA = (g & 1) * 32 + r16;
        int sB = sA + 16;
        unsigned e0 = (unsigned)__shfl((int)w0, sA);
        unsigned e1 = (unsigned)__shfl((int)w1, sA);
        unsigned e2 = (unsigned)__shfl((int)w0, sB);
        unsigned e3 = (unsigned)__shfl((int)w1, sB);
        unsigned f0 = (unsigned)__shfl((int)w2, sA);
        unsigned f1 = (unsigned)__shfl((int)w3, sA);
        unsigned f2 = (unsigned)__shfl((int)w2, sB);
        unsigned f3 = (unsigned)__shfl((int)w3, sB);
        bool hi = (g & 2) != 0;
        union { unsigned u[4]; s16x8 v; } pu;
        pu.u[0] = hi ? f0 : e0;
        pu.u[1] = hi ? f1 : e1;
        pu.u[2] = hi ? f2 : e2;
        pu.u[3] = hi ? f3 : e3;
        pfr[qc] = pu.v;
      }
    }
    __syncthreads();  // A: drains K(t+1) and V(t)

    if (live) {
      u16* Vb = (u16*)(SMc + 32768);
      __builtin_amdgcn_s_setprio(1);
#pragma unroll
      for (int df = 0; df < 8; df++) {
        int vrow = df * 16 + r16;
        s16x8 vf = *(const s16x8*)(Vb + vrow * 64 + (((ks * 4 + g) ^ (vrow & 7)) * 8));
        acc[0][df] = __builtin_amdgcn_mfma_f32_16x16x32_bf16(vf, pfr[0], acc[0][df], 0, 0, 0);
        acc[1][df] = __builtin_amdgcn_mfma_f32_16x16x32_bf16(vf, pfr[1], acc[1][df], 0, 0, 0);
      }
      __builtin_amdgcn_s_setprio(0);
    }
    __syncthreads();  // B: all waves done with Vbuf

    if (t + 1 < nt) STAGE_V(t + 1);
  }

  // ---- pair-merge (ks=0 + ks=1 key-slices) + store; K/V LDS is dead, reuse it ----
  float* ml = (float*)(SMc + 32768);  // [4 waves][2 qc][16 r16][2]
#pragma unroll
  for (int qc = 0; qc < 2; qc++)
    if (g == 0) {
      int mi = ((w * 2 + qc) * 16 + r16) * 2;
      ml[mi] = mrun[qc];
      ml[mi + 1] = lrun[qc];
    }
  __syncthreads();
  int pw = w ^ 1;  // partner wave (other ks, same qs)
  float scale[2];
#pragma unroll
  for (int qc = 0; qc < 2; qc++) {
    float pm = ml[((pw * 2 + qc) * 16 + r16) * 2];
    float pl = ml[((pw * 2 + qc) * 16 + r16) * 2 + 1];
    float ms = fmaxf(mrun[qc], pm);
    float aS = exp2f(mrun[qc] - ms);
    float aP = exp2f(pm - ms);
    float ls = lrun[qc] * aS + pl * aP;
    scale[qc] = aS / ls;
  }
  if (ks == 0) {  // write scaled f32 partials to [0,32K): [qs][row 32][dim-chunk swizzled]
#pragma unroll
    for (int qc = 0; qc < 2; qc++)
#pragma unroll
      for (int df = 0; df < 8; df++) {
        f32x4 v = acc[qc][df] * scale[qc];
        *(f32x4*)(SMc + qs * 16384 + (qc * 16 + r16) * 512 + (((df * 4 + g) ^ (r16 & 7)) * 16)) = v;
      }
  }
  __syncthreads();
  if (ks == 1) {  // merge + store
#pragma unroll
    for (int qc = 0; qc < 2; qc++)
#pragma unroll
      for (int df = 0; df < 8; df++) {
        f32x4 p = *(const f32x4*)(SMc + qs * 16384 + (qc * 16 + r16) * 512 + (((df * 4 + g) ^ (r16 & 7)) * 16));
        f32x4 o = p + acc[qc][df] * scale[qc];
        uint2 pk;
        pk.x = cvtpk(o[0], o[1]);
        pk.y = cvtpk(o[2], o[3]);
        *(uint2*)(O + (size_t)(q0 + qs * 32 + qc * 16 + r16) * 2048 + h * 128 + df * 16 + g * 4) = pk;
      }
  }
}

extern "C" void kernel_launch(void* const* d_in, const int* in_sizes, int n_in,
                              void* d_out, int out_size, void* d_ws, size_t ws_size,
                              hipStream_t stream) {
  const float* hidden = (const float*)d_in[0];
  const float* sinT = (const float*)d_in[1];
  const float* cosT = (const float*)d_in[2];
  // d_in[3] = mask (bool tril) — causal hardcoded
  const float* Wq = (const float*)d_in[4];
  const float* Wk = (const float*)d_in[5];
  const float* Wv = (const float*)d_in[6];
  const float* Wo = (const float*)d_in[7];
  const float* qsc = (const float*)d_in[8];
  const float* ksc = (const float*)d_in[9];
  float* out = (float*)d_out;

  char* ws = (char*)d_ws;
  u16* Xb   = (u16*)(ws + 0);          // [4096][2048]      16.78 MB
  u16* Bqkv = (u16*)(ws + 16777216);   // [3072][2048]      12.58 MB
  u16* Wot  = (u16*)(ws + 29360128);   // [2048][2048]       8.39 MB
  u16* Qraw = (u16*)(ws + 37748736);   // [4096][2048]      16.78 MB
  u16* Kraw = (u16*)(ws + 54525952);   // [4096][512]        4.19 MB
  u16* Vt   = (u16*)(ws + 58720256);   // [512][4096]        4.19 MB
  u16* Oat  = (u16*)(ws + 62914560);   // [4096][2048]      16.78 MB  (end 79.7 MB)

  k_cvt<<<dim3(4096), dim3(256), 0, stream>>>(hidden, Xb);
  k_transpose_cvt<<<dim3(64, 64), dim3(256), 0, stream>>>(Wq, Bqkv, 2048, 2048);
  k_transpose_cvt<<<dim3(16, 64), dim3(256), 0, stream>>>(Wk, Bqkv + 2048 * 2048, 2048, 512);
  k_transpose_cvt<<<dim3(16, 64), dim3(256), 0, stream>>>(Wv, Bqkv + 2560 * 2048, 2048, 512);
  k_transpose_cvt<<<dim3(64, 64), dim3(256), 0, stream>>>(Wo, Wot, 2048, 2048);

  k_gemm<<<dim3(24, 32), dim3(256), 0, stream>>>(Xb, Bqkv, Qraw, Kraw, Vt, (float*)nullptr,
                                                 4096, 3072, 2048, 0);
  k_normrope<<<dim3(4096, 5), dim3(256), 0, stream>>>(Qraw, Kraw, sinT, cosT, qsc, ksc);
  k_attn<<<dim3(1024), dim3(256), 0, stream>>>(Qraw, Kraw, Vt, Oat);
  k_gemm<<<dim3(16, 32), dim3(256), 0, stream>>>(Oat, Wot, (u16*)nullptr, (u16*)nullptr, (u16*)nullptr,
                                                 out, 4096, 2048, 2048, 1);
}

// Round 10
// 258.529 us; speedup vs baseline: 1.1668x; 1.1668x over previous
//
#include <hip/hip_runtime.h>
#include <hip/hip_bf16.h>
#include <stdint.h>

#define T_SEQ 4096
#define KVB 64
#define BM 128
#define BN 128
#define BK 64
#define SCL2 (0.08838834764831845f * 1.44269504088896340f)

typedef unsigned short u16;
typedef __attribute__((ext_vector_type(8))) short s16x8;
typedef __attribute__((ext_vector_type(4))) short s16x4;
typedef __attribute__((ext_vector_type(4))) float f32x4;

__device__ __forceinline__ u16 f2bf(float f) {
  union { float f; unsigned u; } a; a.f = f;
  unsigned r = a.u + 0x7fffu + ((a.u >> 16) & 1u);
  return (u16)(r >> 16);
}
__device__ __forceinline__ float bf2f(u16 b) {
  union { unsigned u; float f; } a; a.u = ((unsigned)b) << 16;
  return a.f;
}
__device__ __forceinline__ unsigned cvtpk(float lo, float hi) {
  unsigned r;
  asm volatile("v_cvt_pk_bf16_f32 %0, %1, %2" : "=v"(r) : "v"(lo), "v"(hi));
  return r;
}

__device__ __forceinline__ void gl_lds16(const void* g, void* l) {
  __builtin_amdgcn_global_load_lds((const __attribute__((address_space(1))) void*)g,
                                   (__attribute__((address_space(3))) void*)l, 16, 0, 0);
}

// ---------------- fused prep: hidden cvt + 4 weight transpose-cvts ----------------
// blocks [0,4096): cvt hidden->Xb; [4096,8192): Wq^T; [8192,9216): Wk^T; [9216,10240): Wv^T;
// [10240,14336): Wo^T. All 256-thread blocks.
__global__ __launch_bounds__(256) void k_prep(const float* __restrict__ hidden, u16* __restrict__ Xb,
                                              const float* __restrict__ Wq, const float* __restrict__ Wk,
                                              const float* __restrict__ Wv, const float* __restrict__ Wo,
                                              u16* __restrict__ Bqkv, u16* __restrict__ Wot) {
  __shared__ float tile[32][33];
  int bid = blockIdx.x;
  if (bid < 4096) {
    int i = (bid * 256 + threadIdx.x) * 8;
    const float4* p = (const float4*)(hidden + i);
    float4 a = p[0], b = p[1];
    s16x8 o;
    o[0] = (short)f2bf(a.x); o[1] = (short)f2bf(a.y); o[2] = (short)f2bf(a.z); o[3] = (short)f2bf(a.w);
    o[4] = (short)f2bf(b.x); o[5] = (short)f2bf(b.y); o[6] = (short)f2bf(b.z); o[7] = (short)f2bf(b.w);
    *(s16x8*)(Xb + i) = o;
    return;
  }
  const float* in;
  u16* out;
  int R, C, l;
  if (bid < 8192)       { in = Wq; out = Bqkv;              R = 2048; C = 2048; l = bid - 4096; }
  else if (bid < 9216)  { in = Wk; out = Bqkv + 2048 * 2048; R = 2048; C = 512;  l = bid - 8192; }
  else if (bid < 10240) { in = Wv; out = Bqkv + 2560 * 2048; R = 2048; C = 512;  l = bid - 9216; }
  else                  { in = Wo; out = Wot;               R = 2048; C = 2048; l = bid - 10240; }
  int nbx = C >> 5;
  int bx = l % nbx, by = l / nbx;
  int c0 = bx * 32, r0 = by * 32;
  int tx = threadIdx.x & 31, ty = threadIdx.x >> 5;
#pragma unroll
  for (int k = 0; k < 4; k++) tile[ty + 8 * k][tx] = in[(size_t)(r0 + ty + 8 * k) * C + c0 + tx];
  __syncthreads();
#pragma unroll
  for (int k = 0; k < 4; k++) out[(size_t)(c0 + ty + 8 * k) * R + r0 + tx] = f2bf(tile[tx][ty + 8 * k]);
}

// ---------------- GEMM: C[m][n] = sum_k A[m][k]*Bt[n][k]  (A,Bt bf16) ----------------
// XCD-bijective block swizzle (grid total % 8 == 0): each XCD gets contiguous m-rows -> A panels L2-held.
__global__ __launch_bounds__(256, 2) void k_gemm(const u16* __restrict__ A, const u16* __restrict__ Bt,
                                                 u16* __restrict__ Cq, u16* __restrict__ Ck, u16* __restrict__ Cvt,
                                                 float* __restrict__ Cf, int M, int N, int Kd, int mode) {
  __shared__ u16 SM[BM * BK + BN * BK];
  u16* As = SM;
  u16* Bs = SM + BM * BK;
  int tid = threadIdx.x, lane = tid & 63, w = tid >> 6;
  int g = lane >> 4, r16 = lane & 15;
  int lidb = blockIdx.y * gridDim.x + blockIdx.x;
  int per = (gridDim.x * gridDim.y) >> 3;
  int nid = (lidb & 7) * per + (lidb >> 3);
  int ty = nid / gridDim.x;
  int m0 = ty * BM, n0 = (nid - ty * gridDim.x) * BN;
  int wr = w >> 1, wc = w & 1;
  f32x4 acc[4][4] = {};

  for (int kt = 0; kt < Kd; kt += BK) {
#pragma unroll
    for (int i = 0; i < 4; i++) {
      int idx = i * 256 + tid;
      int row = idx >> 3, c = idx & 7;
      int cs = c ^ (row & 7);
      gl_lds16(A + (size_t)(m0 + row) * Kd + kt + cs * 8, As + (i * 256 + w * 64) * 8);
    }
#pragma unroll
    for (int i = 0; i < 4; i++) {
      int idx = i * 256 + tid;
      int row = idx >> 3, c = idx & 7;
      int cs = c ^ (row & 7);
      gl_lds16(Bt + (size_t)(n0 + row) * Kd + kt + cs * 8, Bs + (i * 256 + w * 64) * 8);
    }
    __syncthreads();
#pragma unroll
    for (int kk = 0; kk < 2; kk++) {
      s16x8 af[4], bfr[4];
#pragma unroll
      for (int mi = 0; mi < 4; mi++) {
        int row = wr * 64 + mi * 16 + r16;
        af[mi] = *(const s16x8*)(As + row * 64 + (((kk * 4 + g) ^ (row & 7)) * 8));
      }
#pragma unroll
      for (int ni = 0; ni < 4; ni++) {
        int row = wc * 64 + ni * 16 + r16;
        bfr[ni] = *(const s16x8*)(Bs + row * 64 + (((kk * 4 + g) ^ (row & 7)) * 8));
      }
#pragma unroll
      for (int mi = 0; mi < 4; mi++)
#pragma unroll
        for (int ni = 0; ni < 4; ni++)
          acc[mi][ni] = __builtin_amdgcn_mfma_f32_16x16x32_bf16(af[mi], bfr[ni], acc[mi][ni], 0, 0, 0);
    }
    __syncthreads();
  }

#pragma unroll
  for (int mi = 0; mi < 4; mi++) {
    int rowb = m0 + wr * 64 + mi * 16 + g * 4;
#pragma unroll
    for (int ni = 0; ni < 4; ni++) {
      int ncol0 = n0 + wc * 64 + ni * 16;
      int col = ncol0 + r16;
      if (mode == 0) {
        if (ncol0 < 2048) {
#pragma unroll
          for (int j = 0; j < 4; j++) Cq[(size_t)(rowb + j) * 2048 + col] = f2bf(acc[mi][ni][j]);
        } else if (ncol0 < 2560) {
#pragma unroll
          for (int j = 0; j < 4; j++) Ck[(size_t)(rowb + j) * 512 + (col - 2048)] = f2bf(acc[mi][ni][j]);
        } else {
          s16x4 pk;
#pragma unroll
          for (int j = 0; j < 4; j++) pk[j] = (short)f2bf(acc[mi][ni][j]);
          *(s16x4*)(Cvt + (size_t)(col - 2560) * T_SEQ + rowb) = pk;
        }
      } else {
#pragma unroll
        for (int j = 0; j < 4; j++) Cf[(size_t)(rowb + j) * N + col] = acc[mi][ni][j];
      }
    }
  }
}

// ---------------- RMSNorm + RoPE (+ fold attention scale into Q) ----------------
__global__ __launch_bounds__(256) void k_normrope(u16* __restrict__ Q, u16* __restrict__ Kc,
                                                  const float* __restrict__ sinT, const float* __restrict__ cosT,
                                                  const float* __restrict__ qsc, const float* __restrict__ ksc) {
  int t = blockIdx.x;
  int w = threadIdx.x >> 6, lane = threadIdx.x & 63;
  int unit = blockIdx.y * 4 + w;  // 0..15 Q heads, 16..19 K heads
  u16* base;
  const float* sc;
  float fold;
  if (unit < 16) { base = Q + (size_t)t * 2048 + unit * 128; sc = qsc; fold = SCL2; }
  else { base = Kc + (size_t)t * 512 + (unit - 16) * 128; sc = ksc; fold = 1.0f; }
  float x1 = bf2f(base[lane]), x2 = bf2f(base[lane + 64]);
  float ss = x1 * x1 + x2 * x2;
#pragma unroll
  for (int off = 32; off >= 1; off >>= 1) ss += __shfl_xor(ss, off);
  float rinv = rsqrtf(ss * (1.0f / 128.0f) + 1e-6f);
  float n1 = x1 * rinv * sc[lane], n2 = x2 * rinv * sc[lane + 64];
  float s = sinT[t * 64 + lane], c = cosT[t * 64 + lane];
  base[lane] = f2bf((n1 * c - n2 * s) * fold);
  base[lane + 64] = f2bf((n2 * c + n1 * s) * fold);
}

// ---------------- Flash attention (causal GQA) — 2x2 (q-split x key-split) waves [R6 proven] ----------------
// Q [T][2048] bf16 (pre-scaled by SCALE*log2e), Kc [T][512], Vt [512][T], O [T][2048]
// 1024 blocks x 256 thr. Block covers QBLK=64 q-rows; wave (qs,ks) owns 32 q-rows x 32-key slice.
// LDS: K dbuf 2x16KB [0,32K) | V dbuf 2x16KB [32K,64K) | P 4x2KB [64K,72K). Post-loop reused as
// ob f32 accum regions [0,64K) + ml exchange @64K.
__global__ __launch_bounds__(256, 2) void k_attn(const u16* __restrict__ Q, const u16* __restrict__ Kc,
                                                 const u16* __restrict__ Vt, u16* __restrict__ O) {
  __shared__ __align__(16) char SMc[73728];
  int tid = threadIdx.x, lane = tid & 63, w = tid >> 6;
  int g = lane >> 4, r16 = lane & 15;
  int qs = w >> 1, ks = w & 1;

  // XCD chunking (2 heads/XCD -> K/V L2-resident) + LPT (long qb first; backfill via 1024 > resident)
  int bid = blockIdx.x;
  int xcd = bid & 7;
  int lid = bid >> 3;            // 0..127 within XCD
  int h = xcd * 2 + (lid & 1);
  int qb = 63 - (lid >> 1);      // descending work
  int gh = h >> 2;
  int q0 = qb * 64;
  int qwv = q0 + qs * 32;
  int nt = qb + 1;

  s16x8 qf[2][4];
#pragma unroll
  for (int qc = 0; qc < 2; qc++)
#pragma unroll
    for (int dc = 0; dc < 4; dc++)
      qf[qc][dc] = *(const s16x8*)(Q + (size_t)(qwv + qc * 16 + r16) * 2048 + h * 128 + dc * 32 + g * 8);

  auto STAGE = [&](int bb, int tt) {
    int kv0 = tt * KVB;
    u16* Kb = (u16*)(SMc + bb * 16384);
    u16* Vb = (u16*)(SMc + 32768 + bb * 16384);
#pragma unroll
    for (int i = 0; i < 4; i++) {
      int idx = i * 256 + tid;
      int row = idx >> 4, cc = idx & 15;
      int cs = cc ^ (row & 7);
      gl_lds16(Kc + (size_t)(kv0 + row) * 512 + gh * 128 + cs * 8, Kb + (i * 256 + w * 64) * 8);
    }
#pragma unroll
    for (int i = 0; i < 4; i++) {
      int idx = i * 256 + tid;
      int row = idx >> 3, cc = idx & 7;
      int cs = cc ^ (row & 7);
      gl_lds16(Vt + (size_t)(gh * 128 + row) * T_SEQ + kv0 + cs * 8, Vb + (i * 256 + w * 64) * 8);
    }
  };

  f32x4 acc[2][8] = {};
  float mrun[2] = {-3.0e38f, -3.0e38f};
  float lrun[2] = {0.0f, 0.0f};

  STAGE(0, 0);
  __syncthreads();

  for (int t = 0; t < nt; ++t) {
    int kv0 = t * KVB;
    int bb = t & 1;
    STAGE(bb ^ 1, (t + 1 < nt) ? t + 1 : 0);  // prefetch next (wrap = dummy, unread)

    int kvw = kv0 + ks * 32;  // this wave's 32-key slice
    if (kvw <= qwv + 31) {    // wave-uniform causal skip
      u16* Kb = (u16*)(SMc + bb * 16384);
      u16* Vb = (u16*)(SMc + 32768 + bb * 16384);
      char* Pwb = SMc + 65536 + w * 2048;

      // S = K @ Q^T : sv[qc][kc] lane holds key = kvw+kc*16+g*4+reg, q = qwv+qc*16+r16
      f32x4 sv[2][2] = {};
      __builtin_amdgcn_s_setprio(1);
#pragma unroll
      for (int kc = 0; kc < 2; kc++) {
        int krow = ks * 32 + kc * 16 + r16;
#pragma unroll
        for (int dc = 0; dc < 4; dc++) {
          s16x8 kf = *(const s16x8*)((u16*)Kb + krow * 128 + (((dc * 4 + g) ^ (krow & 7)) * 8));
          sv[0][kc] = __builtin_amdgcn_mfma_f32_16x16x32_bf16(kf, qf[0][dc], sv[0][kc], 0, 0, 0);
          sv[1][kc] = __builtin_amdgcn_mfma_f32_16x16x32_bf16(kf, qf[1][dc], sv[1][kc], 0, 0, 0);
        }
      }
      __builtin_amdgcn_s_setprio(0);

#pragma unroll
      for (int qc = 0; qc < 2; qc++) {
        int qg = qwv + qc * 16 + r16;
        bool needmask = (kvw + 31) > (qwv + qc * 16);
        if (needmask) {
#pragma unroll
          for (int kc = 0; kc < 2; kc++)
#pragma unroll
            for (int j2 = 0; j2 < 4; j2++)
              if (kvw + kc * 16 + g * 4 + j2 > qg) sv[qc][kc][j2] = -3.0e38f;
        }
        float mt = sv[qc][0][0];
#pragma unroll
        for (int kc = 0; kc < 2; kc++)
#pragma unroll
          for (int j2 = 0; j2 < 4; j2++) mt = fmaxf(mt, sv[qc][kc][j2]);
        mt = fmaxf(mt, __shfl_xor(mt, 16));
        mt = fmaxf(mt, __shfl_xor(mt, 32));
        // defer-max (T13)
        if (__any(mt > mrun[qc] + 8.0f)) {
          float mnew = fmaxf(mrun[qc], mt);
          float al = exp2f(mrun[qc] - mnew);
          mrun[qc] = mnew;
          lrun[qc] *= al;
#pragma unroll
          for (int df = 0; df < 8; df++) acc[qc][df] = acc[qc][df] * al;
        }
        float rs = 0.0f;
#pragma unroll
        for (int kc = 0; kc < 2; kc++) {
          float p0 = exp2f(sv[qc][kc][0] - mrun[qc]);
          float p1 = exp2f(sv[qc][kc][1] - mrun[qc]);
          float p2 = exp2f(sv[qc][kc][2] - mrun[qc]);
          float p3 = exp2f(sv[qc][kc][3] - mrun[qc]);
          rs += (p0 + p1) + (p2 + p3);
          uint2 pk;
          pk.x = cvtpk(p0, p1);
          pk.y = cvtpk(p2, p3);
          int unit = ((qc << 2) | (kc << 1) | (g >> 1)) ^ (r16 & 7);
          *(uint2*)(Pwb + r16 * 128 + unit * 16 + (g & 1) * 8) = pk;
        }
        rs += __shfl_xor(rs, 16);
        rs += __shfl_xor(rs, 32);
        lrun[qc] += rs;
      }

      // PV: acc[qc][df] lane holds dim = df*16+g*4+reg, q = r16 (keys = this wave's slice)
      __builtin_amdgcn_s_setprio(1);
      s16x8 pf0 = *(const s16x8*)(Pwb + r16 * 128 + (((0 * 4 + g) ^ (r16 & 7)) * 16));
      s16x8 pf1 = *(const s16x8*)(Pwb + r16 * 128 + (((1 * 4 + g) ^ (r16 & 7)) * 16));
#pragma unroll
      for (int df = 0; df < 8; df++) {
        int vrow = df * 16 + r16;
        s16x8 vf = *(const s16x8*)((u16*)Vb + vrow * 64 + (((ks * 4 + g) ^ (vrow & 7)) * 8));
        acc[0][df] = __builtin_amdgcn_mfma_f32_16x16x32_bf16(vf, pf0, acc[0][df], 0, 0, 0);
        acc[1][df] = __builtin_amdgcn_mfma_f32_16x16x32_bf16(vf, pf1, acc[1][df], 0, 0, 0);
      }
      __builtin_amdgcn_s_setprio(0);
    }
    __syncthreads();
  }

  // ---- pair-merge (ks=0 slice + ks=1 slice) + store ----
  float* ml = (float*)(SMc + 65536);  // [4 waves][2 qc][16 r16][2] (P region, dead)
  if (g < 2) {
    float mv = g ? mrun[1] : mrun[0];
    float lv = g ? lrun[1] : lrun[0];
    int mi = ((w * 2 + g) * 16 + r16) * 2;
    ml[mi] = mv;
    ml[mi + 1] = lv;
  }
  __syncthreads();
  int pw = w ^ 1;
  float scale[2];
#pragma unroll
  for (int qc = 0; qc < 2; qc++) {
    float pm = ml[((pw * 2 + qc) * 16 + r16) * 2];
    float pl = ml[((pw * 2 + qc) * 16 + r16) * 2 + 1];
    float ms = fmaxf(mrun[qc], pm);
    float aS = exp2f(mrun[qc] - ms);
    float aP = exp2f(pm - ms);
    float ls = lrun[qc] * aS + pl * aP;
    scale[qc] = aS / ls;
  }
  // write scaled f32 acc to ob region (qs, ks) with row-XOR swizzle
  char* obw = SMc + qs * 16384 + ks * 32768;
#pragma unroll
  for (int qc = 0; qc < 2; qc++)
#pragma unroll
    for (int df = 0; df < 8; df++) {
      f32x4 v = acc[qc][df] * scale[qc];
      int r = qc * 16 + r16;
      int u = df * 4 + g;
      int up = u ^ ((r & 7) << 2);
      *(f32x4*)(obw + r * 512 + up * 16) = v;
    }
  __syncthreads();
  // readout: sum ks0+ks1 copies, convert, coalesced store
#pragma unroll
  for (int it = 0; it < 8; it++) {
    int item = it * 256 + tid;
    int qs2 = item >> 10, rem = item & 1023;
    int r = rem >> 5, u = rem & 31;
    int up = u ^ ((r & 7) << 2);
    f32x4 a = *(const f32x4*)(SMc + qs2 * 16384 + r * 512 + up * 16);
    f32x4 b = *(const f32x4*)(SMc + 32768 + qs2 * 16384 + r * 512 + up * 16);
    f32x4 sSum = a + b;
    uint2 pk;
    pk.x = cvtpk(sSum[0], sSum[1]);
    pk.y = cvtpk(sSum[2], sSum[3]);
    *(uint2*)(O + (size_t)(q0 + qs2 * 32 + r) * 2048 + h * 128 + u * 4) = pk;
  }
}

extern "C" void kernel_launch(void* const* d_in, const int* in_sizes, int n_in,
                              void* d_out, int out_size, void* d_ws, size_t ws_size,
                              hipStream_t stream) {
  const float* hidden = (const float*)d_in[0];
  const float* sinT = (const float*)d_in[1];
  const float* cosT = (const float*)d_in[2];
  // d_in[3] = mask (bool tril) — causal hardcoded
  const float* Wq = (const float*)d_in[4];
  const float* Wk = (const float*)d_in[5];
  const float* Wv = (const float*)d_in[6];
  const float* Wo = (const float*)d_in[7];
  const float* qsc = (const float*)d_in[8];
  const float* ksc = (const float*)d_in[9];
  float* out = (float*)d_out;

  char* ws = (char*)d_ws;
  u16* Xb   = (u16*)(ws + 0);          // [4096][2048]      16.78 MB
  u16* Bqkv = (u16*)(ws + 16777216);   // [3072][2048]      12.58 MB
  u16* Wot  = (u16*)(ws + 29360128);   // [2048][2048]       8.39 MB
  u16* Qraw = (u16*)(ws + 37748736);   // [4096][2048]      16.78 MB
  u16* Kraw = (u16*)(ws + 54525952);   // [4096][512]        4.19 MB
  u16* Vt   = (u16*)(ws + 58720256);   // [512][4096]        4.19 MB
  u16* Oat  = (u16*)(ws + 62914560);   // [4096][2048]      16.78 MB  (end 79.7 MB)

  k_prep<<<dim3(14336), dim3(256), 0, stream>>>(hidden, Xb, Wq, Wk, Wv, Wo, Bqkv, Wot);
  k_gemm<<<dim3(24, 32), dim3(256), 0, stream>>>(Xb, Bqkv, Qraw, Kraw, Vt, (float*)nullptr,
                                                 4096, 3072, 2048, 0);
  k_normrope<<<dim3(4096, 5), dim3(256), 0, stream>>>(Qraw, Kraw, sinT, cosT, qsc, ksc);
  k_attn<<<dim3(1024), dim3(256), 0, stream>>>(Qraw, Kraw, Vt, Oat);
  k_gemm<<<dim3(16, 32), dim3(256), 0, stream>>>(Oat, Wot, (u16*)nullptr, (u16*)nullptr, (u16*)nullptr,
                                                 out, 4096, 2048, 2048, 1);
}